// Round 4
// baseline (333.275 us; speedup 1.0000x reference)
//
#include <hip/hip_runtime.h>
#include <hip/hip_fp16.h>

// MSAAttention: x = e + PE; q,k,v = Linear(x); out = softmax(q k^T) v
// B=8 S=2048 H=512, fp32 in/out. f16 MFMA GEMMs + fp32-math softmax.
//
// Round 10: algorithmic fusion. Three K-loop structures (2-phase, deep ring,
// 8-phase) all plateaued at 10-15% MfmaUtil on these short-K shapes, so the
// S=qk^T GEMM and the softmax are fused into ONE kernel with full-row tiles
// (M=32 x N=2048 x K=512): q-tile swizzled in LDS (shared), per-wave 256-key
// slices with K-fragments direct from XCD-pinned L2 (2 MB, genuinely
// resident), zero barriers in the d-loop, softmax in the epilogue
// (in-register row reduce + 1KB LDS cross-wave combine), P written once.
// Kills the S 64MB write + 128MB softmax round-trip + one launch boundary.
// QKV reverts to the proven R0 gemm6 (2-phase); PV unchanged.

using half8   = __attribute__((ext_vector_type(8))) _Float16;
using half4v  = __attribute__((ext_vector_type(4))) _Float16;
using floatx4 = __attribute__((ext_vector_type(4))) float;

#define BK 32  // halves per K chunk -> 64 B LDS rows (gemm6)

#define VMCNT(N) asm volatile("s_waitcnt vmcnt(" #N ")" ::: "memory")

__device__ __forceinline__ void g2l16(const void* g, void* l) {
  // async global->LDS DMA, 16 B/lane; LDS dest = wave-uniform base + lane*16
  __builtin_amdgcn_global_load_lds((const __attribute__((address_space(1))) void*)g,
                                   (__attribute__((address_space(3))) void*)l, 16, 0, 0);
}

// ---- prep (blocks 0..8191): x16 = f16(embeds + PE)
// ---- cvt  (blocks 8192..11263): wcat f16 [1536][512] + bcat fp32 [1536]
__global__ __launch_bounds__(256) void prep_cvt_kernel(const float* __restrict__ e,
                                                       _Float16* __restrict__ x16,
                                                       const float* __restrict__ wq,
                                                       const float* __restrict__ wk,
                                                       const float* __restrict__ wv,
                                                       const float* __restrict__ bq,
                                                       const float* __restrict__ bk,
                                                       const float* __restrict__ bv,
                                                       _Float16* __restrict__ wcat,
                                                       float* __restrict__ bcat) {
  if (blockIdx.x < 8192) {
    int t = blockIdx.x * 256 + threadIdx.x;  // 2M threads, 4 elems each
    int idx = t * 4;
    int h = idx & 511;
    int s = (idx >> 9) & 2047;
    float4 ev = *(const float4*)(e + idx);
    const float ks = -9.210340371976184f / 256.0f;  // -ln(10000)/256
    float r[4] = {ev.x, ev.y, ev.z, ev.w};
#pragma unroll
    for (int j = 0; j < 4; j++) {
      int hh = h + j;
      int i = (hh < 256) ? hh : (hh - 256);
      float ang = (float)s * __expf((float)i * ks);
      r[j] += (hh < 256) ? __sinf(ang) : __cosf(ang);
    }
    half4v o = {(_Float16)r[0], (_Float16)r[1], (_Float16)r[2], (_Float16)r[3]};
    *(half4v*)(x16 + idx) = o;
  } else {
    int i = (blockIdx.x - 8192) * 256 + threadIdx.x;  // 786432
    int m = i & 262143;
    const float* s = (i < 262144) ? wq : (i < 524288) ? wk : wv;
    wcat[i] = (_Float16)s[m];
    if (i < 512) bcat[i] = bq[i];
    else if (i < 1024) bcat[i] = bk[i - 512];
    else if (i < 1536) bcat[i] = bv[i - 1024];
  }
}

// ---- f16 MFMA GEMM (R0-proven 2-phase): C[m][n] = sum_k A[m][k]*B[n][k] ----
// A [M,K] lda, B [N,K] ldb, k-contiguous. Tile BM x 128, BK=32, 4 waves (2x2),
// wave tile (BM/2) x 64 via 16x16x32 frags. Double-buffered LDS, one barrier
// per K-step, next tile's DMA issued right after the barrier.
// MODE 0: plain 3D grid, plain store.
// MODE 1: QKV — 1D grid 1536, XCD decode, epilogue bias + q/k plain, v transposed.
// MODE 2: 1D grid, XCD decode bz = id&7 (batch->XCD), bx = j & (2^LBX - 1).
template <int BM, typename OutT, int MODE, int LBX>
__global__ __launch_bounds__(256) void gemm6(const _Float16* __restrict__ A,
                                             const _Float16* __restrict__ B,
                                             const float* __restrict__ bias,
                                             OutT* __restrict__ C,
                                             int lda, int ldb, int ldo, int K,
                                             long long sA, long long sB, long long sC,
                                             _Float16* __restrict__ oq,
                                             _Float16* __restrict__ ok,
                                             _Float16* __restrict__ ov) {
  __shared__ _Float16 Ash[2][BM * BK];
  __shared__ _Float16 Bsh[2][128 * BK];
  int bx, by, bz;
  if constexpr (MODE == 1) {
    unsigned i = blockIdx.x;           // 1536 blocks
    unsigned c = i & 7, j = i >> 3;    // j in [0,192)
    by = c * 16 + j / 12;              // XCD c owns by-range [16c,16c+16)
    bx = j % 12;
    bz = 0;
  } else if constexpr (MODE == 2) {
    unsigned i = blockIdx.x;
    unsigned c = i & 7, j = i >> 3;
    bz = c;                            // batch -> XCD: operands L2-resident
    bx = j & ((1u << LBX) - 1);
    by = j >> LBX;
  } else {
    bx = blockIdx.x; by = blockIdx.y; bz = blockIdx.z;
  }
  A += (long long)bz * sA;
  B += (long long)bz * sB;
  C += (long long)bz * sC;
  const int m0 = by * BM, n0 = bx * 128;
  const int tid = threadIdx.x;
  const int lane = tid & 63, wave = tid >> 6;
  constexpr int WM = BM / 2;
  constexpr int MI = WM / 16;
  constexpr int AIt = BM / 64;  // A staging issues per wave (16 rows / issue)
  const int wm = (wave >> 1) * WM, wn = (wave & 1) * 64;
  const int quad = lane >> 4, l16 = lane & 15;
  const int lrow = lane >> 2;       // row within a 16-row staging issue
  const int lcol = (lane & 3) * 8;  // half offset within the 32-half row

  floatx4 acc[MI][4] = {};

  auto issue = [&](int buf, int k0) {
#pragma unroll
    for (int t = 0; t < AIt; t++) {
      int is = wave * AIt + t;
      g2l16(A + (long long)(m0 + is * 16 + lrow) * lda + k0 + lcol, &Ash[buf][is * 16 * BK]);
    }
#pragma unroll
    for (int t = 0; t < 2; t++) {
      int is = wave * 2 + t;
      g2l16(B + (long long)(n0 + is * 16 + lrow) * ldb + k0 + lcol, &Bsh[buf][is * 16 * BK]);
    }
  };

  auto compute = [&](int buf) {
    half8 af[MI], bf[4];
#pragma unroll
    for (int i = 0; i < MI; i++)
      af[i] = *(const half8*)&Ash[buf][(wm + 16 * i + l16) * BK + quad * 8];
#pragma unroll
    for (int i = 0; i < 4; i++)
      bf[i] = *(const half8*)&Bsh[buf][(wn + 16 * i + l16) * BK + quad * 8];
#pragma unroll
    for (int mi = 0; mi < MI; mi++)
#pragma unroll
      for (int ni = 0; ni < 4; ni++)
        acc[mi][ni] = __builtin_amdgcn_mfma_f32_16x16x32_f16(af[mi], bf[ni], acc[mi][ni], 0, 0, 0);
  };

  issue(0, 0);
  for (int k0 = 0; k0 < K; k0 += 2 * BK) {
    __syncthreads();                       // drains tile-k DMA (issued one step ago)
    if (k0 + BK < K) issue(1, k0 + BK);    // prefetch flies during compute(0)
    compute(0);
    __syncthreads();                       // ds_reads of buf0 done; drains buf1 DMA
    if (k0 + 2 * BK < K) issue(0, k0 + 2 * BK);
    compute(1);
  }

  // C/D layout (m89-verified): row(m) = quad*4 + reg, col(n) = lane&15
#pragma unroll
  for (int ni = 0; ni < 4; ni++) {
    const int n = n0 + wn + 16 * ni + l16;
    float bv = 0.0f;
    if constexpr (MODE == 1) bv = bias[n];
#pragma unroll
    for (int mi = 0; mi < MI; mi++) {
      const int mg = m0 + wm + 16 * mi + quad * 4;
#pragma unroll
      for (int rr = 0; rr < 4; rr++) {
        float v = acc[mi][ni][rr] + bv;
        if constexpr (MODE == 1) {
          int m = mg + rr;
          if (n < 512) oq[m * 512 + n] = (_Float16)v;
          else if (n < 1024) ok[m * 512 + (n - 512)] = (_Float16)v;
          else ov[(n - 1024) * 16384 + m] = (_Float16)v;  // V^T
        } else {
          C[(long long)(mg + rr) * ldo + n] = (OutT)v;
        }
      }
    }
  }
}

// ---- fused S=qk^T + softmax: P[row][key], per block 32 rows x 2048 keys ----
// Grid 512 = 8 batches (XCD-pinned via i&7) x 64 row-blocks. 8 waves; wave w
// owns keys [256w, 256w+256). Q-tile (32x512 f16 = 32 KB) in LDS, 16B-slot
// XOR-swizzled (slot s of row r holds global slot s^(r&7)) so the af
// ds_read_b128 (row in l16, stride 1 KB) hits 8 distinct slots + broadcast =
// conflict-free. K-fragments loaded straight from L2 (k16 slice 2 MB,
// XCD-resident), double-buffered in registers, NO barriers in the d-loop.
// Epilogue: row max/sum in-register (shfl over l16) + [32][8] LDS cross-wave
// combine; P = exp(s-max)/sum stored f16.
__global__ __launch_bounds__(512, 2) void qk_softmax_kernel(const _Float16* __restrict__ q16,
                                                            const _Float16* __restrict__ k16,
                                                            _Float16* __restrict__ P) {
  __shared__ _Float16 Qs[32 * 512];
  __shared__ float redM[32][8];
  __shared__ float redS[32][8];

  const unsigned i = blockIdx.x;
  const int bz = i & 7;        // batch -> XCD
  const int rb = i >> 3;       // row-block 0..63
  const _Float16* q = q16 + ((long long)bz * 2048 + rb * 32) * 512;
  const _Float16* k = k16 + (long long)bz * 2048 * 512;
  _Float16* p = P + ((long long)bz * 2048 + rb * 32) * 2048;

  const int tid = threadIdx.x;
  const int lane = tid & 63, wave = tid >> 6;
  const int l16 = lane & 15, quad = lane >> 4;
  const int n0 = wave * 256;  // this wave's key-slice

  // stage Q: wave w stages rows 4w..4w+3; one 1KB issue per row; global
  // source pre-swizzled per-lane so LDS (linear lane*16) holds slot^(r&7)
#pragma unroll
  for (int r2 = 0; r2 < 4; r2++) {
    int row = wave * 4 + r2;
    g2l16(q + row * 512 + ((lane ^ (row & 7)) * 8), &Qs[row * 512]);
  }
  VMCNT(0);
  __syncthreads();

  // d-loop: 16 steps of 32 halves; per step 2 af (LDS) + 16 bf (global, 2
  // halves double-buffered) + 32 MFMA. acc[mi][ni]: rows 16mi+4quad+rr,
  // key = n0 + 16ni + l16.
  floatx4 acc[2][16] = {};
  const _Float16* kb = k + (long long)(n0 + l16) * 512 + quad * 8;

  half8 bX[8], bY[8];
  auto loadB = [&](half8* bf, int ds, int h) {
#pragma unroll
    for (int j = 0; j < 8; j++)
      bf[j] = *(const half8*)(kb + (h * 8 + j) * 16 * 512 + ds * 32);
  };
  auto mm = [&](half8* bf, half8 a0, half8 a1, int h) {
#pragma unroll
    for (int j = 0; j < 8; j++) {
      acc[0][h * 8 + j] = __builtin_amdgcn_mfma_f32_16x16x32_f16(a0, bf[j], acc[0][h * 8 + j], 0, 0, 0);
      acc[1][h * 8 + j] = __builtin_amdgcn_mfma_f32_16x16x32_f16(a1, bf[j], acc[1][h * 8 + j], 0, 0, 0);
    }
  };

  loadB(bX, 0, 0);
  for (int ds = 0; ds < 16; ds++) {
    const int sw = ((ds * 4 + quad) ^ (l16 & 7)) * 8;
    half8 a0 = *(const half8*)&Qs[l16 * 512 + sw];         // rows 0-15
    half8 a1 = *(const half8*)&Qs[(16 + l16) * 512 + sw];  // rows 16-31
    loadB(bY, ds, 1);
    mm(bX, a0, a1, 0);
    if (ds + 1 < 16) loadB(bX, ds + 1, 0);
    mm(bY, a0, a1, 1);
  }

  // ---- fused softmax epilogue ----
  float gmax[2][4], gsum[2][4];
#pragma unroll
  for (int mi = 0; mi < 2; mi++)
#pragma unroll
    for (int rr = 0; rr < 4; rr++) {
      float m = acc[mi][0][rr];
#pragma unroll
      for (int ni = 1; ni < 16; ni++) m = fmaxf(m, acc[mi][ni][rr]);
#pragma unroll
      for (int o = 8; o >= 1; o >>= 1) m = fmaxf(m, __shfl_xor(m, o));
      gmax[mi][rr] = m;
    }
  if (l16 == 0) {
#pragma unroll
    for (int mi = 0; mi < 2; mi++)
#pragma unroll
      for (int rr = 0; rr < 4; rr++) redM[16 * mi + 4 * quad + rr][wave] = gmax[mi][rr];
  }
  __syncthreads();
#pragma unroll
  for (int mi = 0; mi < 2; mi++)
#pragma unroll
    for (int rr = 0; rr < 4; rr++) {
      const int row = 16 * mi + 4 * quad + rr;
      float m = redM[row][0];
#pragma unroll
      for (int w = 1; w < 8; w++) m = fmaxf(m, redM[row][w]);
      float s = 0.0f;
#pragma unroll
      for (int ni = 0; ni < 16; ni++) {
        float e = __expf(acc[mi][ni][rr] - m);
        acc[mi][ni][rr] = e;
        s += e;
      }
#pragma unroll
      for (int o = 8; o >= 1; o >>= 1) s += __shfl_xor(s, o);
      gsum[mi][rr] = s;
    }
  if (l16 == 0) {
#pragma unroll
    for (int mi = 0; mi < 2; mi++)
#pragma unroll
      for (int rr = 0; rr < 4; rr++) redS[16 * mi + 4 * quad + rr][wave] = gsum[mi][rr];
  }
  __syncthreads();
#pragma unroll
  for (int mi = 0; mi < 2; mi++)
#pragma unroll
    for (int rr = 0; rr < 4; rr++) {
      const int row = 16 * mi + 4 * quad + rr;
      float s = 0.0f;
#pragma unroll
      for (int w = 0; w < 8; w++) s += redS[row][w];
      const float inv = 1.0f / s;
#pragma unroll
      for (int ni = 0; ni < 16; ni++)
        p[(long long)row * 2048 + n0 + 16 * ni + l16] = (_Float16)(acc[mi][ni][rr] * inv);
    }
}

// ---- softmax over f16 rows of S (2048 wide), fp32 math, f16 in place ----
// (small-ws fallback path only)
__global__ __launch_bounds__(256) void softmax_kernel(_Float16* __restrict__ S) {
  const int lane = threadIdx.x & 63;
  const int wave = threadIdx.x >> 6;
  const long long row = (long long)blockIdx.x * 4 + wave;
  _Float16* srow = S + row * 2048;
  float v[32];
  float mx = -3.4e38f;
#pragma unroll
  for (int pass = 0; pass < 4; pass++) {
    half8 f = *(const half8*)(srow + (pass * 64 + lane) * 8);
#pragma unroll
    for (int j = 0; j < 8; j++) {
      float x = (float)f[j];
      v[pass * 8 + j] = x;
      mx = fmaxf(mx, x);
    }
  }
#pragma unroll
  for (int o = 32; o > 0; o >>= 1) mx = fmaxf(mx, __shfl_xor(mx, o));
  float sum = 0.0f;
#pragma unroll
  for (int j = 0; j < 32; j++) {
    v[j] = __expf(v[j] - mx);
    sum += v[j];
  }
#pragma unroll
  for (int o = 32; o > 0; o >>= 1) sum += __shfl_xor(sum, o);
  const float inv = 1.0f / sum;
#pragma unroll
  for (int pass = 0; pass < 4; pass++) {
    half8 o8;
#pragma unroll
    for (int j = 0; j < 8; j++) o8[j] = (_Float16)(v[pass * 8 + j] * inv);
    *(half8*)(srow + (pass * 64 + lane) * 8) = o8;
  }
}

extern "C" void kernel_launch(void* const* d_in, const int* in_sizes, int n_in,
                              void* d_out, int out_size, void* d_ws, size_t ws_size,
                              hipStream_t stream) {
  const float* e  = (const float*)d_in[0];
  const float* Wq = (const float*)d_in[1];
  const float* bq = (const float*)d_in[2];
  const float* Wk = (const float*)d_in[3];
  const float* bk = (const float*)d_in[4];
  const float* Wv = (const float*)d_in[5];
  const float* bv = (const float*)d_in[6];
  float* out = (float*)d_out;
  char* ws = (char*)d_ws;

  const long long MiB = 1024LL * 1024LL;
  // big: P f16 [8][2048][2048] = 64 MiB at once; small: per-batch 8 MiB
  const bool big = ws_size >= (size_t)(115 * MiB);
  const long long base = big ? 64 * MiB : 16 * MiB;  // x16 needs 16 MiB at head

  _Float16* S    = (_Float16*)ws;
  _Float16* x16  = (_Float16*)ws;  // overlays S head; dead before S written
  _Float16* q16  = (_Float16*)(ws + base);
  _Float16* k16  = (_Float16*)(ws + base + 16 * MiB);
  _Float16* vt   = (_Float16*)(ws + base + 32 * MiB);
  _Float16* wcat = (_Float16*)(ws + base + 48 * MiB);   // 1.5 MiB
  float*    bcat = (float*)(ws + base + 48 * MiB + 1536 * 1024);

  prep_cvt_kernel<<<11264, 256, 0, stream>>>(e, x16, Wq, Wk, Wv, bq, bk, bv, wcat, bcat);

  // fused QKV: M=16384 N=1536 K=512; XCD-decoded 1D grid; q/k plain, v transposed
  gemm6<128, _Float16, 1, 0><<<1536, 256, 0, stream>>>(
      x16, wcat, bcat, (_Float16*)nullptr, 512, 512, 0, 512, 0, 0, 0, q16, k16, vt);

  if (big) {
    // P = softmax(q k^T) fused: 512 blocks (8 batch x 64 row-blocks)
    qk_softmax_kernel<<<512, 512, 0, stream>>>(q16, k16, S);
    // out = P v: BM=64; batch->XCD, bx = j&3
    gemm6<64, float, 2, 2><<<1024, 256, 0, stream>>>(
        S, vt, nullptr, out, 2048, 16384, 512, 2048,
        4194304LL, 2048LL, 1048576LL, nullptr, nullptr, nullptr);
  } else {
    for (int b = 0; b < 8; b++) {
      gemm6<128, _Float16, 0, 0><<<dim3(16, 16, 1), 256, 0, stream>>>(
          q16 + (long long)b * 1048576, k16 + (long long)b * 1048576, nullptr, S,
          512, 512, 2048, 512, 0, 0, 0, nullptr, nullptr, nullptr);
      softmax_kernel<<<512, 256, 0, stream>>>(S);
      gemm6<64, float, 0, 0><<<dim3(4, 32, 1), 256, 0, stream>>>(
          S, vt + (long long)b * 2048, nullptr, out + (long long)b * 1048576,
          2048, 16384, 512, 2048, 0, 0, 0, nullptr, nullptr, nullptr);
    }
  }
}

// Round 5
// 266.512 us; speedup vs baseline: 1.2505x; 1.2505x over previous
//
#include <hip/hip_runtime.h>
#include <hip/hip_fp16.h>

// MSAAttention: x = e + PE; q,k,v = Linear(x); out = softmax(q k^T) v
// B=8 S=2048 H=512, fp32 in/out. f16 MFMA GEMMs + fp32-math softmax.
//
// Round 11: measured recombination of the two proven schedules.
//  - QKV:  gemm6 2-phase (R0-proven, 65 us). 8-phase lost here purely to
//    grid quantization (384 blocks @ 1/CU = 1.5 rounds).
//  - S=qk^T: gemm9 8-phase 256x256, grid 512 = clean 2 rounds (R3-proven).
//  - PV:   gemm9 8-phase 128x256, grid 256 = 1 round, NT=32 deep pipeline
//    (R3-proven).
//  - prep/softmax unchanged.
// R0 total 270.7 (all 2-phase); R3 total 279.5 (8-phase everywhere, QKV
// regressed +24). This combo takes the best measured variant per launch.

using half8   = __attribute__((ext_vector_type(8))) _Float16;
using half4v  = __attribute__((ext_vector_type(4))) _Float16;
using floatx4 = __attribute__((ext_vector_type(4))) float;

#define BK 32  // halves per K chunk -> 64 B LDS rows (gemm6)

#define VMCNT(N) asm volatile("s_waitcnt vmcnt(" #N ")" ::: "memory")

__device__ __forceinline__ void g2l16(const void* g, void* l) {
  // async global->LDS DMA, 16 B/lane; LDS dest = wave-uniform base + lane*16
  __builtin_amdgcn_global_load_lds((const __attribute__((address_space(1))) void*)g,
                                   (__attribute__((address_space(3))) void*)l, 16, 0, 0);
}

// ---- prep (blocks 0..8191): x16 = f16(embeds + PE)
// ---- cvt  (blocks 8192..11263): wcat f16 [1536][512] + bcat fp32 [1536]
__global__ __launch_bounds__(256) void prep_cvt_kernel(const float* __restrict__ e,
                                                       _Float16* __restrict__ x16,
                                                       const float* __restrict__ wq,
                                                       const float* __restrict__ wk,
                                                       const float* __restrict__ wv,
                                                       const float* __restrict__ bq,
                                                       const float* __restrict__ bk,
                                                       const float* __restrict__ bv,
                                                       _Float16* __restrict__ wcat,
                                                       float* __restrict__ bcat) {
  if (blockIdx.x < 8192) {
    int t = blockIdx.x * 256 + threadIdx.x;  // 2M threads, 4 elems each
    int idx = t * 4;
    int h = idx & 511;
    int s = (idx >> 9) & 2047;
    float4 ev = *(const float4*)(e + idx);
    const float ks = -9.210340371976184f / 256.0f;  // -ln(10000)/256
    float r[4] = {ev.x, ev.y, ev.z, ev.w};
#pragma unroll
    for (int j = 0; j < 4; j++) {
      int hh = h + j;
      int i = (hh < 256) ? hh : (hh - 256);
      float ang = (float)s * __expf((float)i * ks);
      r[j] += (hh < 256) ? __sinf(ang) : __cosf(ang);
    }
    half4v o = {(_Float16)r[0], (_Float16)r[1], (_Float16)r[2], (_Float16)r[3]};
    *(half4v*)(x16 + idx) = o;
  } else {
    int i = (blockIdx.x - 8192) * 256 + threadIdx.x;  // 786432
    int m = i & 262143;
    const float* s = (i < 262144) ? wq : (i < 524288) ? wk : wv;
    wcat[i] = (_Float16)s[m];
    if (i < 512) bcat[i] = bq[i];
    else if (i < 1024) bcat[i] = bk[i - 512];
    else if (i < 1536) bcat[i] = bv[i - 1024];
  }
}

// ---- gemm6 (R0-proven 2-phase): C[m][n] = sum_k A[m][k]*B[n][k] ----
// A [M,K] lda, B [N,K] ldb, k-contiguous. Tile BM x 128, BK=32, 4 waves (2x2),
// wave tile (BM/2) x 64 via 16x16x32 frags. Double-buffered LDS, one barrier
// per K-step, next tile's DMA issued right after the barrier.
// MODE 0: plain 3D grid, plain store.
// MODE 1: QKV — 1D grid 1536, XCD decode, epilogue bias + q/k plain, v transposed.
// MODE 2: 1D grid, XCD decode bz = id&7 (batch->XCD), bx = j & (2^LBX - 1).
template <int BM, typename OutT, int MODE, int LBX>
__global__ __launch_bounds__(256) void gemm6(const _Float16* __restrict__ A,
                                             const _Float16* __restrict__ B,
                                             const float* __restrict__ bias,
                                             OutT* __restrict__ C,
                                             int lda, int ldb, int ldo, int K,
                                             long long sA, long long sB, long long sC,
                                             _Float16* __restrict__ oq,
                                             _Float16* __restrict__ ok,
                                             _Float16* __restrict__ ov) {
  __shared__ _Float16 Ash[2][BM * BK];
  __shared__ _Float16 Bsh[2][128 * BK];
  int bx, by, bz;
  if constexpr (MODE == 1) {
    unsigned i = blockIdx.x;           // 1536 blocks
    unsigned c = i & 7, j = i >> 3;    // j in [0,192)
    by = c * 16 + j / 12;              // XCD c owns by-range [16c,16c+16)
    bx = j % 12;
    bz = 0;
  } else if constexpr (MODE == 2) {
    unsigned i = blockIdx.x;
    unsigned c = i & 7, j = i >> 3;
    bz = c;                            // batch -> XCD: operands L2-resident
    bx = j & ((1u << LBX) - 1);
    by = j >> LBX;
  } else {
    bx = blockIdx.x; by = blockIdx.y; bz = blockIdx.z;
  }
  A += (long long)bz * sA;
  B += (long long)bz * sB;
  C += (long long)bz * sC;
  const int m0 = by * BM, n0 = bx * 128;
  const int tid = threadIdx.x;
  const int lane = tid & 63, wave = tid >> 6;
  constexpr int WM = BM / 2;
  constexpr int MI = WM / 16;
  constexpr int AIt = BM / 64;  // A staging issues per wave (16 rows / issue)
  const int wm = (wave >> 1) * WM, wn = (wave & 1) * 64;
  const int quad = lane >> 4, l16 = lane & 15;
  const int lrow = lane >> 2;       // row within a 16-row staging issue
  const int lcol = (lane & 3) * 8;  // half offset within the 32-half row

  floatx4 acc[MI][4] = {};

  auto issue = [&](int buf, int k0) {
#pragma unroll
    for (int t = 0; t < AIt; t++) {
      int is = wave * AIt + t;
      g2l16(A + (long long)(m0 + is * 16 + lrow) * lda + k0 + lcol, &Ash[buf][is * 16 * BK]);
    }
#pragma unroll
    for (int t = 0; t < 2; t++) {
      int is = wave * 2 + t;
      g2l16(B + (long long)(n0 + is * 16 + lrow) * ldb + k0 + lcol, &Bsh[buf][is * 16 * BK]);
    }
  };

  auto compute = [&](int buf) {
    half8 af[MI], bf[4];
#pragma unroll
    for (int i = 0; i < MI; i++)
      af[i] = *(const half8*)&Ash[buf][(wm + 16 * i + l16) * BK + quad * 8];
#pragma unroll
    for (int i = 0; i < 4; i++)
      bf[i] = *(const half8*)&Bsh[buf][(wn + 16 * i + l16) * BK + quad * 8];
#pragma unroll
    for (int mi = 0; mi < MI; mi++)
#pragma unroll
      for (int ni = 0; ni < 4; ni++)
        acc[mi][ni] = __builtin_amdgcn_mfma_f32_16x16x32_f16(af[mi], bf[ni], acc[mi][ni], 0, 0, 0);
  };

  issue(0, 0);
  for (int k0 = 0; k0 < K; k0 += 2 * BK) {
    __syncthreads();                       // drains tile-k DMA (issued one step ago)
    if (k0 + BK < K) issue(1, k0 + BK);    // prefetch flies during compute(0)
    compute(0);
    __syncthreads();                       // ds_reads of buf0 done; drains buf1 DMA
    if (k0 + 2 * BK < K) issue(0, k0 + 2 * BK);
    compute(1);
  }

  // C/D layout (m89-verified): row(m) = quad*4 + reg, col(n) = lane&15
#pragma unroll
  for (int ni = 0; ni < 4; ni++) {
    const int n = n0 + wn + 16 * ni + l16;
    float bv = 0.0f;
    if constexpr (MODE == 1) bv = bias[n];
#pragma unroll
    for (int mi = 0; mi < MI; mi++) {
      const int mg = m0 + wm + 16 * mi + quad * 4;
#pragma unroll
      for (int rr = 0; rr < 4; rr++) {
        float v = acc[mi][ni][rr] + bv;
        if constexpr (MODE == 1) {
          int m = mg + rr;
          if (n < 512) oq[m * 512 + n] = (_Float16)v;
          else if (n < 1024) ok[m * 512 + (n - 512)] = (_Float16)v;
          else ov[(n - 1024) * 16384 + m] = (_Float16)v;  // V^T
        } else {
          C[(long long)(mg + rr) * ldo + n] = (OutT)v;
        }
      }
    }
  }
}

// ---- gemm9 (R3-proven 8-phase): deep-pipelined f16 MFMA GEMM ----
// Tile BM x BN, BK=64, 8 waves (2M x 4N), per-wave (BM/2) x (BN/4).
// LDS: [2 bufs][2 kk-halves][rows][32 halves]; each kk-half contiguous.
// Stage slots per tile t: p1=A1[t+1], p2=B1[t+1], p3=A0[t+2], p4=B0[t+2];
// counted vmcnt(IA+IB) at p4 (vmcnt(0) only last 2 tiles). XOR-swizzled LDS
// reads (slot = quad ^ ((l16>>1)&3)) with inverse swizzle on the staging
// source address. setprio(1) around each MFMA cluster.
// MODE 2: 1D grid, bz = id&7 (batch->XCD), bx = j & (2^LBX-1).
template <int BM, int BN, typename OutT, int MODE, int LBX>
__global__ __launch_bounds__(512, 2) void gemm9(const _Float16* __restrict__ A,
                                                const _Float16* __restrict__ B,
                                                const float* __restrict__ bias,
                                                OutT* __restrict__ C,
                                                int lda, int ldb, int ldo, int K,
                                                long long sA, long long sB, long long sC,
                                                _Float16* __restrict__ oq,
                                                _Float16* __restrict__ ok,
                                                _Float16* __restrict__ ov) {
  constexpr int MI = BM / 32;   // per-wave m-frags
  constexpr int NI = BN / 64;   // per-wave n-frags
  constexpr int NIH = NI / 2;
  constexpr int IA = BM / 128;  // gload issues / wave / A-half
  constexpr int IB = BN / 128;

  __shared__ _Float16 Ash[2][2][BM * 32];
  __shared__ _Float16 Bsh[2][2][BN * 32];

  int bx, by, bz;
  if constexpr (MODE == 1) {
    unsigned i = blockIdx.x;
    unsigned c = i & 7, j = i >> 3;
    by = c * 8 + (j & 7);
    bx = j >> 3;
    bz = 0;
  } else {
    unsigned i = blockIdx.x;
    unsigned c = i & 7, j = i >> 3;
    bz = c;                          // batch -> XCD: operands L2-resident
    bx = j & ((1u << LBX) - 1);
    by = j >> LBX;
  }
  A += (long long)bz * sA;
  B += (long long)bz * sB;
  C += (long long)bz * sC;
  const int m0 = by * BM, n0 = bx * BN;
  const int tid = threadIdx.x;
  const int lane = tid & 63, wave = tid >> 6;
  const int l16 = lane & 15, quad = lane >> 4;
  const int wrow = (wave >> 2) * (BM / 2);
  const int wcol = (wave & 3) * (BN / 4);
  const int srow = lane >> 2;                              // staging row in issue
  const int scol = 8 * ((lane & 3) ^ ((lane >> 3) & 3));   // inverse-swizzled col
  const int rsw = (l16 >> 1) & 3;                          // read-side swizzle

  // staging source base pointers (k-invariant)
  const _Float16* aSrc[IA];
  const _Float16* bSrc[IB];
#pragma unroll
  for (int i = 0; i < IA; i++)
    aSrc[i] = A + (long long)(m0 + (wave * IA + i) * 16 + srow) * lda + scol;
#pragma unroll
  for (int i = 0; i < IB; i++)
    bSrc[i] = B + (long long)(n0 + (wave * IB + i) * 16 + srow) * ldb + scol;

  auto stA = [&](int tile, int kk) {
#pragma unroll
    for (int i = 0; i < IA; i++)
      g2l16(aSrc[i] + tile * 64 + kk * 32,
            (_Float16*)Ash[tile & 1][kk] + (wave * IA + i) * 512);
  };
  auto stB = [&](int tile, int kk) {
#pragma unroll
    for (int i = 0; i < IB; i++)
      g2l16(bSrc[i] + tile * 64 + kk * 32,
            (_Float16*)Bsh[tile & 1][kk] + (wave * IB + i) * 512);
  };

  floatx4 acc[MI][NI] = {};
  half8 af[MI], bf[NI];

  auto ldA = [&](int buf, int kk) {
#pragma unroll
    for (int mi = 0; mi < MI; mi++)
      af[mi] = *(const half8*)(Ash[buf][kk] + (wrow + mi * 16 + l16) * 32 + (quad ^ rsw) * 8);
  };
  auto ldB0 = [&](int buf, int kk) {
#pragma unroll
    for (int j = 0; j < NIH; j++)
      bf[j] = *(const half8*)(Bsh[buf][kk] + (wcol + j * 16 + l16) * 32 + (quad ^ rsw) * 8);
  };
  auto ldB1 = [&](int buf, int kk) {
#pragma unroll
    for (int j = 0; j < NIH; j++)
      bf[NIH + j] = *(const half8*)(Bsh[buf][kk] + (wcol + (NIH + j) * 16 + l16) * 32 + (quad ^ rsw) * 8);
  };
  auto mm0 = [&]() {
#pragma unroll
    for (int mi = 0; mi < MI; mi++)
#pragma unroll
      for (int j = 0; j < NIH; j++)
        acc[mi][j] = __builtin_amdgcn_mfma_f32_16x16x32_f16(af[mi], bf[j], acc[mi][j], 0, 0, 0);
  };
  auto mm1 = [&]() {
#pragma unroll
    for (int mi = 0; mi < MI; mi++)
#pragma unroll
      for (int j = 0; j < NIH; j++)
        acc[mi][NIH + j] =
            __builtin_amdgcn_mfma_f32_16x16x32_f16(af[mi], bf[NIH + j], acc[mi][NIH + j], 0, 0, 0);
  };

#define MFMA_SEG(MMX)                                 \
  __builtin_amdgcn_s_barrier();                       \
  asm volatile("s_waitcnt lgkmcnt(0)" ::: "memory");  \
  __builtin_amdgcn_sched_barrier(0);                  \
  __builtin_amdgcn_s_setprio(1);                      \
  MMX();                                              \
  __builtin_amdgcn_s_setprio(0);                      \
  __builtin_amdgcn_sched_barrier(0);                  \
  __builtin_amdgcn_s_barrier();

  const int NT = K / 64;
  // prologue: tile0 complete + tile1 kk0 halves (FIFO order matters)
  stA(0, 0); stB(0, 0); stA(0, 1); stB(0, 1); stA(1, 0); stB(1, 0);
  if constexpr (IA + IB == 4) { VMCNT(4); } else { VMCNT(3); }
  __builtin_amdgcn_s_barrier();

  for (int t = 0; t < NT; ++t) {
    const int buf = t & 1;
    const bool s1 = (t + 1 < NT), s2 = (t + 2 < NT);
    // p1 (kk0, n-lo) | stage A1[t+1] (other buf, region dead since t-1 p4)
    ldA(buf, 0); ldB0(buf, 0);
    if (s1) stA(t + 1, 1);
    MFMA_SEG(mm0);
    // p2 (kk0, n-hi) | stage B1[t+1]
    ldB1(buf, 0);
    if (s1) stB(t + 1, 1);
    MFMA_SEG(mm1);
    // p3 (kk1, n-lo) | stage A0[t+2] (this buf, region dead since p2)
    ldA(buf, 1); ldB0(buf, 1);
    if (s2) stA(t + 2, 0);
    MFMA_SEG(mm0);
    // p4 (kk1, n-hi) | stage B0[t+2]; counted vmcnt covers next tile's reads
    ldB1(buf, 1);
    if (s2) stB(t + 2, 0);
    if (t < NT - 2) {
      if constexpr (IA + IB == 4) { VMCNT(4); } else { VMCNT(3); }
    } else {
      VMCNT(0);
    }
    MFMA_SEG(mm1);
  }
#undef MFMA_SEG

  // C/D layout (m89-verified): row(m) = quad*4 + reg, col(n) = lane&15
#pragma unroll
  for (int ni = 0; ni < NI; ni++) {
    const int n = n0 + wcol + 16 * ni + l16;
    float bv = 0.0f;
    if constexpr (MODE == 1) bv = bias[n];
#pragma unroll
    for (int mi = 0; mi < MI; mi++) {
      const int mg = m0 + wrow + 16 * mi + quad * 4;
#pragma unroll
      for (int rr = 0; rr < 4; rr++) {
        float v = acc[mi][ni][rr] + bv;
        if constexpr (MODE == 1) {
          int m = mg + rr;
          if (n < 512) oq[m * 512 + n] = (_Float16)v;
          else if (n < 1024) ok[m * 512 + (n - 512)] = (_Float16)v;
          else ov[(n - 1024) * 16384 + m] = (_Float16)v;  // V^T
        } else {
          C[(long long)(mg + rr) * ldo + n] = (OutT)v;
        }
      }
    }
  }
}

// ---- softmax over f16 rows of S (2048 wide), fp32 math, f16 in place ----
__global__ __launch_bounds__(256) void softmax_kernel(_Float16* __restrict__ S) {
  const int lane = threadIdx.x & 63;
  const int wave = threadIdx.x >> 6;
  const long long row = (long long)blockIdx.x * 4 + wave;
  _Float16* srow = S + row * 2048;
  float v[32];
  float mx = -3.4e38f;
#pragma unroll
  for (int pass = 0; pass < 4; pass++) {
    half8 f = *(const half8*)(srow + (pass * 64 + lane) * 8);
#pragma unroll
    for (int j = 0; j < 8; j++) {
      float x = (float)f[j];
      v[pass * 8 + j] = x;
      mx = fmaxf(mx, x);
    }
  }
#pragma unroll
  for (int o = 32; o > 0; o >>= 1) mx = fmaxf(mx, __shfl_xor(mx, o));
  float sum = 0.0f;
#pragma unroll
  for (int j = 0; j < 32; j++) {
    v[j] = __expf(v[j] - mx);
    sum += v[j];
  }
#pragma unroll
  for (int o = 32; o > 0; o >>= 1) sum += __shfl_xor(sum, o);
  const float inv = 1.0f / sum;
#pragma unroll
  for (int pass = 0; pass < 4; pass++) {
    half8 o8;
#pragma unroll
    for (int j = 0; j < 8; j++) o8[j] = (_Float16)(v[pass * 8 + j] * inv);
    *(half8*)(srow + (pass * 64 + lane) * 8) = o8;
  }
}

extern "C" void kernel_launch(void* const* d_in, const int* in_sizes, int n_in,
                              void* d_out, int out_size, void* d_ws, size_t ws_size,
                              hipStream_t stream) {
  const float* e  = (const float*)d_in[0];
  const float* Wq = (const float*)d_in[1];
  const float* bq = (const float*)d_in[2];
  const float* Wk = (const float*)d_in[3];
  const float* bk = (const float*)d_in[4];
  const float* Wv = (const float*)d_in[5];
  const float* bv = (const float*)d_in[6];
  float* out = (float*)d_out;
  char* ws = (char*)d_ws;

  const long long MiB = 1024LL * 1024LL;
  // big: S f16 [8][2048][2048] = 64 MiB at once; small: per-batch 8 MiB
  const bool big = ws_size >= (size_t)(115 * MiB);
  const long long base = big ? 64 * MiB : 16 * MiB;  // x16 needs 16 MiB at head

  _Float16* S    = (_Float16*)ws;
  _Float16* x16  = (_Float16*)ws;  // overlays S head; dead before S written
  _Float16* q16  = (_Float16*)(ws + base);
  _Float16* k16  = (_Float16*)(ws + base + 16 * MiB);
  _Float16* vt   = (_Float16*)(ws + base + 32 * MiB);
  _Float16* wcat = (_Float16*)(ws + base + 48 * MiB);   // 1.5 MiB
  float*    bcat = (float*)(ws + base + 48 * MiB + 1536 * 1024);

  prep_cvt_kernel<<<11264, 256, 0, stream>>>(e, x16, Wq, Wk, Wv, bq, bk, bv, wcat, bcat);

  // fused QKV: M=16384 N=1536 K=512; 2-phase gemm6 (best measured here);
  // q/k plain, v transposed
  gemm6<128, _Float16, 1, 0><<<1536, 256, 0, stream>>>(
      x16, wcat, bcat, (_Float16*)nullptr, 512, 512, 0, 512, 0, 0, 0, q16, k16, vt);

  if (big) {
    // S = q k^T batched: M=N=2048 K=512 f16 out; 8-phase 256x256, grid 512
    // = clean 2 rounds (best measured here)
    gemm9<256, 256, _Float16, 2, 3><<<512, 512, 0, stream>>>(
        q16, k16, nullptr, S, 512, 512, 2048, 512,
        1048576LL, 1048576LL, 4194304LL, nullptr, nullptr, nullptr);
    softmax_kernel<<<4096, 256, 0, stream>>>(S);
    // out = P v: M=2048 N=512 K=2048; 8-phase 128x256, grid 256 = 1 round,
    // NT=32 (best measured here)
    gemm9<128, 256, float, 2, 1><<<256, 512, 0, stream>>>(
        S, vt, nullptr, out, 2048, 16384, 512, 2048,
        4194304LL, 2048LL, 1048576LL, nullptr, nullptr, nullptr);
  } else {
    for (int b = 0; b < 8; b++) {
      gemm6<128, _Float16, 0, 0><<<dim3(16, 16, 1), 256, 0, stream>>>(
          q16 + (long long)b * 1048576, k16 + (long long)b * 1048576, nullptr, S,
          512, 512, 2048, 512, 0, 0, 0, nullptr, nullptr, nullptr);
      softmax_kernel<<<512, 256, 0, stream>>>(S);
      gemm6<64, float, 0, 0><<<dim3(4, 32, 1), 256, 0, stream>>>(
          S, vt + (long long)b * 2048, nullptr, out + (long long)b * 1048576,
          2048, 16384, 512, 2048, 0, 0, 0, nullptr, nullptr, nullptr);
    }
  }
}